// Round 1
// baseline (31.873 us; speedup 1.0000x reference)
//
#include <hip/hip_runtime.h>
#include <math.h>

// Problem constants (from reference setup_inputs)
#define BS    16
#define NQ    100
#define NCLS  2
#define Q_DIM (BS * NQ)     // 1600
#define T_DIM 320
#define P_DIM 72
#define ROW   (5 + 2 * P_DIM)  // 149 floats per tgt row

// ---------------- Kernel 1: per-target weights ----------------
// weights[t] = sqrt(S / v[t]) / max_t' sqrt(S / v[t'])  ==  sqrt(min_t' v / v[t])
__global__ void weights_kernel(const float* __restrict__ tgt,
                               float* __restrict__ w) {
    __shared__ float vc[T_DIM];
    __shared__ float minv_s;
    int t = threadIdx.x;
    if (t < T_DIM) {
        const float* xs = tgt + t * ROW + 5;
        int cnt = 0;
        #pragma unroll
        for (int p = 0; p < P_DIM; ++p) cnt += (xs[p] >= 0.0f) ? 1 : 0;
        vc[t] = (float)cnt;
    }
    __syncthreads();
    if (t == 0) {
        float m = vc[0];
        for (int i = 1; i < T_DIM; ++i) m = fminf(m, vc[i]);
        minv_s = m;
    }
    __syncthreads();
    if (t < T_DIM) w[t] = sqrtf(minv_s / vc[t]);
}

// ---------------- Kernel 2: cost matrix ----------------
// Block tile: 64 t  x  16 q  (4 waves x 4 q/thread).
// threadIdx: t_local = tx & 63 (lane), wave = tx >> 6 -> q uniform per wave
//  -> tgt reads from LDS (stride 149, odd -> conflict-free),
//     curve/logit reads scalar, out writes coalesced.
#define TT  64
#define QPT 4

__global__ __launch_bounds__(256) void cost_kernel(
    const float* __restrict__ logits,   // [Q,2]
    const float* __restrict__ curves,   // [Q,8]
    const float* __restrict__ tgt,      // [T,149]
    const int*   __restrict__ tgt_ids,  // [T]
    const float* __restrict__ w,        // [T]
    float*       __restrict__ out)      // [Q,T]
{
    __shared__ float s_tgt[TT * ROW];   // 64*149*4 = 38144 B
    const int tx = threadIdx.x;
    const int t_base = blockIdx.y * TT;

    // Stage 64 contiguous tgt rows linearly into LDS (fully coalesced).
    const float* src = tgt + t_base * ROW;
    for (int i = tx; i < TT * ROW; i += 256) s_tgt[i] = src[i];
    __syncthreads();

    const int t_local = tx & 63;
    const int wave    = tx >> 6;              // 0..3, uniform per wave
    const int t       = t_base + t_local;
    const float* srow = s_tgt + t_local * ROW;

    const float ly = srow[1], uy = srow[2], lx = srow[3], ux = srow[4];
    const int   id = tgt_ids[t];
    const float wt = w[t] * 0.1f;             // CURVES_W / 10

    const int q0 = blockIdx.x * (4 * QPT) + wave * QPT;

    float b0[QPT], b1[QPT], b2[QPT], b3[QPT], base_cost[QPT];
    #pragma unroll
    for (int j = 0; j < QPT; ++j) {
        const int q = q0 + j;
        const float* c = curves + q * 8;
        b0[j] = c[0]; b1[j] = c[1]; b2[j] = c[2]; b3[j] = c[3];
        const float b4 = c[4], b5 = c[5], b6 = c[6], b7 = c[7];
        const float l0 = logits[q * 2 + 0], l1 = logits[q * 2 + 1];
        const float m  = fmaxf(l0, l1);
        const float e0 = expf(l0 - m), e1 = expf(l1 - m);
        const float inv = 1.0f / (e0 + e1);
        const float prob = (id == 0) ? e0 * inv : e1 * inv;
        const float cl = (fabsf(b4 - ly) + fabsf(b6 - lx)) * 0.5f;
        const float cu = (fabsf(b5 - uy) + fabsf(b7 - ux)) * 0.5f;
        base_cost[j] = -prob + cl + cu;
    }

    float acc[QPT] = {0.0f, 0.0f, 0.0f, 0.0f};
    #pragma unroll 8
    for (int p = 0; p < P_DIM; ++p) {
        const float xs = srow[5 + p];
        const float ys = srow[5 + P_DIM + p];
        const bool valid = (xs >= 0.0f);
        #pragma unroll
        for (int j = 0; j < QPT; ++j) {
            const float v = ((b3[j] * ys + b2[j]) * ys + b1[j]) * ys + b0[j];
            const float d = fabsf(xs - v);
            acc[j] += valid ? d : 0.0f;
        }
    }

    #pragma unroll
    for (int j = 0; j < QPT; ++j) {
        const int q = q0 + j;
        out[q * T_DIM + t] = base_cost[j] + acc[j] * wt;
    }
}

extern "C" void kernel_launch(void* const* d_in, const int* in_sizes, int n_in,
                              void* d_out, int out_size, void* d_ws, size_t ws_size,
                              hipStream_t stream) {
    const float* logits  = (const float*)d_in[0];  // [16,100,2]
    const float* curves  = (const float*)d_in[1];  // [16,100,8]
    const float* tgt     = (const float*)d_in[2];  // [320,149]
    const int*   tgt_ids = (const int*)d_in[3];    // [320]
    float* out = (float*)d_out;                    // [16,100,320]
    float* w   = (float*)d_ws;                     // 320 floats scratch

    weights_kernel<<<1, T_DIM, 0, stream>>>(tgt, w);

    dim3 grid(Q_DIM / (4 * QPT), T_DIM / TT);      // (100, 5)
    cost_kernel<<<grid, 256, 0, stream>>>(logits, curves, tgt, tgt_ids, w, out);
}

// Round 2
// 19.657 us; speedup vs baseline: 1.6215x; 1.6215x over previous
//
#include <hip/hip_runtime.h>
#include <math.h>

// Problem constants (from reference setup_inputs)
#define BS    16
#define NQ    100
#define Q_DIM (BS * NQ)        // 1600
#define T_DIM 320
#define P_DIM 72
#define ROW   (5 + 2 * P_DIM)  // 149 floats per tgt row

#define TT  64                 // t-tile per block
#define QPT 4                  // q per thread (4 waves x 4 = 16 q per block)

// Single fused kernel. Grid (100, 5), 256 threads.
// - stages this block's 64 tgt rows into LDS (linear, coalesced)
// - redundantly computes valid-counts for ALL 320 rows (L2-resident reads)
//   and a parallel min-reduce -> weights w[t] = sqrt(min_vc / vc[t])
// - main p-loop: per-wave-uniform q (scalar curve loads), lane-varying t
//   (LDS stride 149 = odd -> conflict-free), coalesced out writes.
__global__ __launch_bounds__(256) void cost_kernel(
    const float* __restrict__ logits,   // [Q,2]
    const float* __restrict__ curves,   // [Q,8]
    const float* __restrict__ tgt,      // [T,149]
    const int*   __restrict__ tgt_ids,  // [T]
    float*       __restrict__ out)      // [Q,T]
{
    __shared__ float s_tgt[TT * ROW];   // 38144 B
    __shared__ float s_vc[T_DIM];       // 1280 B
    __shared__ float s_min;

    const int tx = threadIdx.x;
    const int t_base = blockIdx.y * TT;

    // ---- Phase A: stage this block's 64 contiguous tgt rows into LDS ----
    const float* src = tgt + t_base * ROW;
    for (int i = tx; i < TT * ROW; i += 256) s_tgt[i] = src[i];

    // ---- Phase B: valid-counts for all 320 rows (from global; L2-hot) ----
    for (int t = tx; t < T_DIM; t += 256) {
        const float* xs = tgt + t * ROW + 5;
        int cnt = 0;
        #pragma unroll 8
        for (int p = 0; p < P_DIM; ++p) cnt += (xs[p] >= 0.0f) ? 1 : 0;
        s_vc[t] = (float)cnt;
    }
    __syncthreads();

    // ---- Phase C: parallel min-reduce over 320 counts ----
    if (tx < 64) {
        float m = s_vc[tx];
        #pragma unroll
        for (int k = 1; k < T_DIM / 64; ++k) m = fminf(m, s_vc[tx + k * 64]);
        #pragma unroll
        for (int d = 32; d > 0; d >>= 1) m = fminf(m, __shfl_xor(m, d, 64));
        if (tx == 0) s_min = m;
    }
    __syncthreads();

    // ---- Phase D: per-thread constants ----
    const int t_local = tx & 63;
    const int wave    = tx >> 6;              // 0..3, uniform per wave
    const int t       = t_base + t_local;
    const float* srow = s_tgt + t_local * ROW;

    const float ly = srow[1], uy = srow[2], lx = srow[3], ux = srow[4];
    const int   id = tgt_ids[t];
    const float wt = sqrtf(s_min / s_vc[t]) * 0.1f;   // CURVES_W / 10

    const int q0 = blockIdx.x * (4 * QPT) + wave * QPT;

    float b0[QPT], b1[QPT], b2[QPT], b3[QPT], base_cost[QPT];
    #pragma unroll
    for (int j = 0; j < QPT; ++j) {
        const int q = q0 + j;
        const float* c = curves + q * 8;
        b0[j] = c[0]; b1[j] = c[1]; b2[j] = c[2]; b3[j] = c[3];
        const float b4 = c[4], b5 = c[5], b6 = c[6], b7 = c[7];
        const float l0 = logits[q * 2 + 0], l1 = logits[q * 2 + 1];
        const float m  = fmaxf(l0, l1);
        const float e0 = expf(l0 - m), e1 = expf(l1 - m);
        const float inv = 1.0f / (e0 + e1);
        const float prob = (id == 0) ? e0 * inv : e1 * inv;
        const float cl = (fabsf(b4 - ly) + fabsf(b6 - lx)) * 0.5f;
        const float cu = (fabsf(b5 - uy) + fabsf(b7 - ux)) * 0.5f;
        base_cost[j] = -prob + cl + cu;
    }

    // ---- Phase E: main p-loop ----
    float acc[QPT] = {0.0f, 0.0f, 0.0f, 0.0f};
    #pragma unroll 8
    for (int p = 0; p < P_DIM; ++p) {
        const float xs = srow[5 + p];
        const float ys = srow[5 + P_DIM + p];
        const float vmask = (xs >= 0.0f) ? 1.0f : 0.0f;
        #pragma unroll
        for (int j = 0; j < QPT; ++j) {
            const float v = ((b3[j] * ys + b2[j]) * ys + b1[j]) * ys + b0[j];
            acc[j] = fmaf(vmask, fabsf(xs - v), acc[j]);   // abs folds as input mod
        }
    }

    #pragma unroll
    for (int j = 0; j < QPT; ++j) {
        const int q = q0 + j;
        out[q * T_DIM + t] = base_cost[j] + acc[j] * wt;
    }
}

extern "C" void kernel_launch(void* const* d_in, const int* in_sizes, int n_in,
                              void* d_out, int out_size, void* d_ws, size_t ws_size,
                              hipStream_t stream) {
    const float* logits  = (const float*)d_in[0];  // [16,100,2]
    const float* curves  = (const float*)d_in[1];  // [16,100,8]
    const float* tgt     = (const float*)d_in[2];  // [320,149]
    const int*   tgt_ids = (const int*)d_in[3];    // [320]
    float* out = (float*)d_out;                    // [16,100,320]

    dim3 grid(Q_DIM / (4 * QPT), T_DIM / TT);      // (100, 5)
    cost_kernel<<<grid, 256, 0, stream>>>(logits, curves, tgt, tgt_ids, out);
}